// Round 1
// baseline (934.542 us; speedup 1.0000x reference)
//
#include <hip/hip_runtime.h>

// LIF spiking net forward:
//   I = input_spikes (B*T, n_in) @ W^T (n_in, n_out)   [fp32 GEMM]
//   scan over t: v = v*DECAY + I_t; s = (v-1 > 0); v *= (1-s)
// Stage 1 writes I into d_out; stage 2 scans in-place (each thread owns a
// full (b,o) chain, reads I[t] then overwrites with spike s[t]).

#define TILE 64

__global__ __launch_bounds__(256) void lif_gemm(const float* __restrict__ S,
                                                const float* __restrict__ W,
                                                float* __restrict__ I,
                                                int M, int N, int K) {
    __shared__ float As[TILE][TILE + 1];
    __shared__ float Bs[TILE][TILE + 1];
    const int m0 = blockIdx.x * TILE;
    const int n0 = blockIdx.y * TILE;
    const int tid = threadIdx.x;
    const int tx = tid & 15;   // 16 cols of threads
    const int ty = tid >> 4;   // 16 rows of threads

    float acc[4][4] = {{0.f, 0.f, 0.f, 0.f}};

    for (int k0 = 0; k0 < K; k0 += TILE) {
        // Stage 64x64 tiles of A (spikes) and B (W), both row-major K-contiguous.
        // 4096 floats per tile = 1024 float4 loads; 256 threads x 4.
#pragma unroll
        for (int p = 0; p < 4; ++p) {
            const int idx = p * 256 + tid;   // 0..1023
            const int r = idx >> 4;          // 0..63
            const int c = (idx & 15) << 2;   // 0..60 step 4
            const float4 a = *reinterpret_cast<const float4*>(
                S + (size_t)(m0 + r) * K + k0 + c);
            As[r][c + 0] = a.x; As[r][c + 1] = a.y;
            As[r][c + 2] = a.z; As[r][c + 3] = a.w;
            const float4 b = *reinterpret_cast<const float4*>(
                W + (size_t)(n0 + r) * K + k0 + c);
            Bs[r][c + 0] = b.x; Bs[r][c + 1] = b.y;
            Bs[r][c + 2] = b.z; Bs[r][c + 3] = b.w;
        }
        __syncthreads();

#pragma unroll
        for (int kk = 0; kk < TILE; ++kk) {
            float av[4], bv[4];
#pragma unroll
            for (int i = 0; i < 4; ++i) av[i] = As[ty * 4 + i][kk];
#pragma unroll
            for (int j = 0; j < 4; ++j) bv[j] = Bs[tx * 4 + j][kk];
#pragma unroll
            for (int i = 0; i < 4; ++i)
#pragma unroll
                for (int j = 0; j < 4; ++j)
                    acc[i][j] = fmaf(av[i], bv[j], acc[i][j]);
        }
        __syncthreads();
    }

#pragma unroll
    for (int i = 0; i < 4; ++i) {
#pragma unroll
        for (int j = 0; j < 4; ++j) {
            I[(size_t)(m0 + ty * 4 + i) * N + n0 + tx * 4 + j] = acc[i][j];
        }
    }
}

__global__ __launch_bounds__(256) void lif_scan(float* __restrict__ IO,
                                                int B, int T, int NO) {
    const int idx = blockIdx.x * blockDim.x + threadIdx.x;
    if (idx >= B * NO) return;
    const int b = idx / NO;
    const int o = idx % NO;
    float* p = IO + (size_t)b * T * NO + o;

    const float DECAY = 0.95122942450071400910f;  // exp(-1/20) rounded to f32
    float v = 0.f;
    for (int t = 0; t < T; ++t) {
        const float cur = p[(size_t)t * NO];
        v = v * DECAY + cur;
        const float s = (v - 1.0f > 0.0f) ? 1.0f : 0.0f;
        v *= (1.0f - s);
        p[(size_t)t * NO] = s;
    }
}

extern "C" void kernel_launch(void* const* d_in, const int* in_sizes, int n_in,
                              void* d_out, int out_size, void* d_ws, size_t ws_size,
                              hipStream_t stream) {
    const float* S = (const float*)d_in[0];   // (B, T, n_in) binary spikes, fp32
    const float* W = (const float*)d_in[1];   // (n_out, n_in), fp32
    float* out = (float*)d_out;               // (B, T, n_out), fp32

    const int K = 1024;                 // n_in
    const int N = 512;                  // n_out
    const int M = in_sizes[0] / K;      // B*T = 32000
    const int B = 32;
    const int T = M / B;                // 1000

    dim3 grid(M / TILE, N / TILE);      // 500 x 8
    lif_gemm<<<grid, 256, 0, stream>>>(S, W, out, M, N, K);

    const int chains = B * N;           // 16384
    lif_scan<<<(chains + 255) / 256, 256, 0, stream>>>(out, B, T, N);
}

// Round 2
// 343.081 us; speedup vs baseline: 2.7240x; 2.7240x over previous
//
#include <hip/hip_runtime.h>

// LIF spiking net forward, v2 — sparse gather formulation.
//   S is binary (~5% ones):  I[m,:] = sum over active k of W[:,k]  (fp32 exact,
//   ascending-k order == bit-identical to v1's fmaf dense sum which passed
//   with absmax 0.0)
// k1: S (131 MB) -> 1-bit mask (4 MB, in d_ws)
// k2: gather-GEMM using mask + W staged transposed/swizzled in LDS -> I in d_out
// k3: LIF scan in-place on d_out (t-unrolled for memory-level parallelism)

#define N_IN   1024
#define N_OUT  512
#define MASK_WORDS 32               // 1024 bits per row
#define NCHUNK 16                   // n-columns per gather block (64 KB LDS)
#define NCHUNKS (N_OUT / NCHUNK)    // 32
#define ROWS_PER_BLOCK 256
#define DECAY_F 0.95122942450071400910f

// ---------- kernel 1: float spikes -> bitmask ----------
__global__ __launch_bounds__(256) void spikes_to_mask(
        const float* __restrict__ S, unsigned int* __restrict__ mask, int nwords) {
    int g = blockIdx.x * blockDim.x + threadIdx.x;   // one 32-bit word each
    if (g >= nwords) return;
    const float4* p = reinterpret_cast<const float4*>(S) + (size_t)g * 8;
    unsigned int m = 0;
#pragma unroll
    for (int q = 0; q < 8; ++q) {
        float4 v = p[q];
        m |= (v.x != 0.f ? 1u : 0u) << (q * 4 + 0);
        m |= (v.y != 0.f ? 1u : 0u) << (q * 4 + 1);
        m |= (v.z != 0.f ? 1u : 0u) << (q * 4 + 2);
        m |= (v.w != 0.f ? 1u : 0u) << (q * 4 + 3);
    }
    mask[g] = m;
}

// ---------- kernel 2: sparse gather GEMM ----------
// grid = NCHUNKS * (M/ROWS_PER_BLOCK); LDS holds W[n0:n0+16][0:1024] transposed
// to k-major with an XOR swizzle on the n-quad so both staging writes and
// gather reads stay at the ds bank floor.
__global__ __launch_bounds__(256) void gather_gemm(
        const unsigned int* __restrict__ mask,
        const float* __restrict__ W,      // (N_OUT, N_IN) row-major
        float* __restrict__ I) {          // (M, N_OUT)
    __shared__ float wlds[N_IN * NCHUNK]; // 64 KB
    const int chunk = blockIdx.x & (NCHUNKS - 1);
    const int mgrp  = blockIdx.x >> 5;
    const int n0 = chunk * NCHUNK;
    const int m0 = mgrp * ROWS_PER_BLOCK;
    const int tid = threadIdx.x;

    // stage + transpose + swizzle: thread covers k = kb*256+tid
#pragma unroll
    for (int kb = 0; kb < 4; ++kb) {
        const int k = kb * 256 + tid;
        const int sw = (k >> 1) & 3;
#pragma unroll
        for (int rq = 0; rq < 4; ++rq) {
            float4 v;
            v.x = W[(size_t)(n0 + rq * 4 + 0) * N_IN + k];
            v.y = W[(size_t)(n0 + rq * 4 + 1) * N_IN + k];
            v.z = W[(size_t)(n0 + rq * 4 + 2) * N_IN + k];
            v.w = W[(size_t)(n0 + rq * 4 + 3) * N_IN + k];
            *reinterpret_cast<float4*>(&wlds[k * NCHUNK + ((rq ^ sw) << 2)]) = v;
        }
    }
    __syncthreads();

    const int mr = tid >> 2;   // 0..63: row within group of 64
    const int nq = tid & 3;    // n-quad 0..3 within the 16-wide chunk

#pragma unroll 1
    for (int rg = 0; rg < ROWS_PER_BLOCK / 64; ++rg) {
        const int m = m0 + rg * 64 + mr;
        const unsigned int* mrow = mask + (size_t)m * MASK_WORDS;
        float4 acc = {0.f, 0.f, 0.f, 0.f};
#pragma unroll
        for (int wq = 0; wq < 8; ++wq) {
            uint4 mw = reinterpret_cast<const uint4*>(mrow)[wq];
            unsigned long long lo = (unsigned long long)mw.x |
                                    ((unsigned long long)mw.y << 32);
            unsigned long long hi = (unsigned long long)mw.z |
                                    ((unsigned long long)mw.w << 32);
            int kbase = wq * 128;
            while (lo) {
                int b = __builtin_ctzll(lo);
                lo &= lo - 1;
                int k = kbase + b;
                const float4 wv = *reinterpret_cast<const float4*>(
                    &wlds[k * NCHUNK + ((nq ^ ((k >> 1) & 3)) << 2)]);
                acc.x += wv.x; acc.y += wv.y; acc.z += wv.z; acc.w += wv.w;
            }
            while (hi) {
                int b = __builtin_ctzll(hi);
                hi &= hi - 1;
                int k = kbase + 64 + b;
                const float4 wv = *reinterpret_cast<const float4*>(
                    &wlds[k * NCHUNK + ((nq ^ ((k >> 1) & 3)) << 2)]);
                acc.x += wv.x; acc.y += wv.y; acc.z += wv.z; acc.w += wv.w;
            }
        }
        *reinterpret_cast<float4*>(&I[(size_t)m * N_OUT + n0 + (nq << 2)]) = acc;
    }
}

// ---------- kernel 3: LIF scan, in-place, t-unrolled ----------
#define UNROLL_T 40
__global__ __launch_bounds__(256) void lif_scan2(float* __restrict__ IO, int T) {
    const int idx = blockIdx.x * blockDim.x + threadIdx.x;  // chain id
    const int b = idx >> 9, o = idx & (N_OUT - 1);
    float* p = IO + (size_t)b * T * N_OUT + o;
    float v = 0.f;
    for (int t0 = 0; t0 < T; t0 += UNROLL_T) {
        float c[UNROLL_T];
#pragma unroll
        for (int j = 0; j < UNROLL_T; ++j) c[j] = p[(size_t)(t0 + j) * N_OUT];
#pragma unroll
        for (int j = 0; j < UNROLL_T; ++j) {
            v = v * DECAY_F + c[j];
            float s = (v > 1.0f) ? 1.0f : 0.f;
            v *= (1.f - s);
            c[j] = s;
        }
#pragma unroll
        for (int j = 0; j < UNROLL_T; ++j) p[(size_t)(t0 + j) * N_OUT] = c[j];
    }
}

// ---------- fallback (ws too small): v1 dense path ----------
#define TILE 64
__global__ __launch_bounds__(256) void lif_gemm(const float* __restrict__ S,
                                                const float* __restrict__ W,
                                                float* __restrict__ I,
                                                int M, int N, int K) {
    __shared__ float As[TILE][TILE + 1];
    __shared__ float Bs[TILE][TILE + 1];
    const int m0 = blockIdx.x * TILE;
    const int n0 = blockIdx.y * TILE;
    const int tid = threadIdx.x;
    const int tx = tid & 15;
    const int ty = tid >> 4;
    float acc[4][4] = {{0.f, 0.f, 0.f, 0.f}};
    for (int k0 = 0; k0 < K; k0 += TILE) {
#pragma unroll
        for (int p = 0; p < 4; ++p) {
            const int idx = p * 256 + tid;
            const int r = idx >> 4;
            const int c = (idx & 15) << 2;
            const float4 a = *reinterpret_cast<const float4*>(
                S + (size_t)(m0 + r) * K + k0 + c);
            As[r][c + 0] = a.x; As[r][c + 1] = a.y;
            As[r][c + 2] = a.z; As[r][c + 3] = a.w;
            const float4 b = *reinterpret_cast<const float4*>(
                W + (size_t)(n0 + r) * K + k0 + c);
            Bs[r][c + 0] = b.x; Bs[r][c + 1] = b.y;
            Bs[r][c + 2] = b.z; Bs[r][c + 3] = b.w;
        }
        __syncthreads();
#pragma unroll
        for (int kk = 0; kk < TILE; ++kk) {
            float av[4], bv[4];
#pragma unroll
            for (int i = 0; i < 4; ++i) av[i] = As[ty * 4 + i][kk];
#pragma unroll
            for (int j = 0; j < 4; ++j) bv[j] = Bs[tx * 4 + j][kk];
#pragma unroll
            for (int i = 0; i < 4; ++i)
#pragma unroll
                for (int j = 0; j < 4; ++j)
                    acc[i][j] = fmaf(av[i], bv[j], acc[i][j]);
        }
        __syncthreads();
    }
#pragma unroll
    for (int i = 0; i < 4; ++i)
#pragma unroll
        for (int j = 0; j < 4; ++j)
            I[(size_t)(m0 + ty * 4 + i) * N + n0 + tx * 4 + j] = acc[i][j];
}

__global__ __launch_bounds__(256) void lif_scan(float* __restrict__ IO,
                                                int B, int T, int NO) {
    const int idx = blockIdx.x * blockDim.x + threadIdx.x;
    if (idx >= B * NO) return;
    const int b = idx / NO;
    const int o = idx % NO;
    float* p = IO + (size_t)b * T * NO + o;
    float v = 0.f;
    for (int t = 0; t < T; ++t) {
        const float cur = p[(size_t)t * NO];
        v = v * DECAY_F + cur;
        const float s = (v - 1.0f > 0.0f) ? 1.0f : 0.0f;
        v *= (1.0f - s);
        p[(size_t)t * NO] = s;
    }
}

extern "C" void kernel_launch(void* const* d_in, const int* in_sizes, int n_in,
                              void* d_out, int out_size, void* d_ws, size_t ws_size,
                              hipStream_t stream) {
    const float* S = (const float*)d_in[0];   // (B, T, n_in) binary spikes, fp32
    const float* W = (const float*)d_in[1];   // (n_out, n_in), fp32
    float* out = (float*)d_out;               // (B, T, n_out), fp32

    const int K = N_IN;
    const int M = in_sizes[0] / K;            // B*T = 32000
    const int B = 32;
    const int T = M / B;                      // 1000

    const size_t mask_bytes = (size_t)M * MASK_WORDS * sizeof(unsigned int); // 4 MB

    if (ws_size >= mask_bytes && (M % ROWS_PER_BLOCK) == 0) {
        unsigned int* mask = (unsigned int*)d_ws;
        const int nwords = M * MASK_WORDS;
        spikes_to_mask<<<(nwords + 255) / 256, 256, 0, stream>>>(S, mask, nwords);
        gather_gemm<<<NCHUNKS * (M / ROWS_PER_BLOCK), 256, 0, stream>>>(mask, W, out);
        lif_scan2<<<(B * N_OUT) / 256, 256, 0, stream>>>(out, T);
    } else {
        dim3 grid(M / TILE, N_OUT / TILE);
        lif_gemm<<<grid, 256, 0, stream>>>(S, W, out, M, N_OUT, K);
        lif_scan<<<(B * N_OUT + 255) / 256, 256, 0, stream>>>(out, B, T, N_OUT);
    }
}

// Round 3
// 165.131 us; speedup vs baseline: 5.6594x; 2.0776x over previous
//
#include <hip/hip_runtime.h>

// LIF spiking net forward, v3 — whole-wave-per-row sparse gather from L2.
//   S binary (~5% ones):  I[m,:] = sum over active k (ascending) of W[:,k]
//   (bit-identical fp32 order to v1/v2 which passed with absmax 0.0)
// k0: transpose W (512x1024) -> W_T (1024x512) in d_ws  (L2-resident, 2 MB)
// k1: gather_rows: one wave per row m; ballot builds the k-mask in-wave
//     (uniform -> SALU ctz walk, no divergence); per active k the wave reads
//     W_T[k][0:512] from L2 and accumulates in registers -> I in d_out
// k2: LIF scan in-place on d_out (t-unrolled)

#define N_IN   1024
#define N_OUT  512
#define DECAY_F 0.95122942450071400910f

// ---------- kernel 0: W (n,k) -> W_T (k,n) ----------
__global__ __launch_bounds__(256) void transpose_w(const float* __restrict__ W,
                                                   float* __restrict__ WT) {
    __shared__ float t[32][33];
    const int k0 = blockIdx.x * 32;          // gridDim.x = N_IN/32 = 32
    const int n0 = blockIdx.y * 32;          // gridDim.y = N_OUT/32 = 16
    const int lx = threadIdx.x & 31;
    const int ly = threadIdx.x >> 5;         // 8 rows of 32 threads
#pragma unroll
    for (int r = ly; r < 32; r += 8)
        t[r][lx] = W[(size_t)(n0 + r) * N_IN + k0 + lx];
    __syncthreads();
#pragma unroll
    for (int r = ly; r < 32; r += 8)
        WT[(size_t)(k0 + r) * N_OUT + n0 + lx] = t[lx][r];
}

// ---------- kernel 1: per-row gather ----------
__global__ __launch_bounds__(256) void gather_rows(
        const float* __restrict__ S,      // (M, N_IN) binary fp32
        const float* __restrict__ WT,     // (N_IN, N_OUT)
        float* __restrict__ I, int M) {   // (M, N_OUT)
    const int wid  = blockIdx.x * 4 + (threadIdx.x >> 6);  // wave id == row
    const int lane = threadIdx.x & 63;
    if (wid >= M) return;

    const float* srow = S + (size_t)wid * N_IN;
    float4 a0 = {0.f, 0.f, 0.f, 0.f};
    float4 a1 = {0.f, 0.f, 0.f, 0.f};

    // preload the full S row: 16 coalesced b32 loads (one per 64-k group)
    float sv[16];
#pragma unroll
    for (int g = 0; g < 16; ++g) sv[g] = srow[g * 64 + lane];

#pragma unroll
    for (int g = 0; g < 16; ++g) {
        unsigned long long m = __ballot(sv[g] != 0.0f);  // wave-uniform
        while (m) {
            const int b = __builtin_ctzll(m);
            m &= m - 1;
            const int k = g * 64 + b;                    // ascending
            const float* wp = WT + (size_t)k * N_OUT + lane * 4;
            const float4 w0 = *reinterpret_cast<const float4*>(wp);
            const float4 w1 = *reinterpret_cast<const float4*>(wp + 256);
            a0.x += w0.x; a0.y += w0.y; a0.z += w0.z; a0.w += w0.w;
            a1.x += w1.x; a1.y += w1.y; a1.z += w1.z; a1.w += w1.w;
        }
    }

    float* op = I + (size_t)wid * N_OUT + lane * 4;
    *reinterpret_cast<float4*>(op) = a0;
    *reinterpret_cast<float4*>(op + 256) = a1;
}

// ---------- kernel 2: LIF scan, in-place, t-unrolled ----------
#define UNROLL_T 40
__global__ __launch_bounds__(256) void lif_scan2(float* __restrict__ IO, int T) {
    const int idx = blockIdx.x * blockDim.x + threadIdx.x;  // chain id
    const int b = idx >> 9, o = idx & (N_OUT - 1);
    float* p = IO + (size_t)b * T * N_OUT + o;
    float v = 0.f;
    for (int t0 = 0; t0 < T; t0 += UNROLL_T) {
        float c[UNROLL_T];
#pragma unroll
        for (int j = 0; j < UNROLL_T; ++j) c[j] = p[(size_t)(t0 + j) * N_OUT];
#pragma unroll
        for (int j = 0; j < UNROLL_T; ++j) {
            v = v * DECAY_F + c[j];
            float s = (v > 1.0f) ? 1.0f : 0.f;
            v *= (1.f - s);
            c[j] = s;
        }
#pragma unroll
        for (int j = 0; j < UNROLL_T; ++j) p[(size_t)(t0 + j) * N_OUT] = c[j];
    }
}

// ---------- fallback (ws too small): v1 dense path ----------
#define TILE 64
__global__ __launch_bounds__(256) void lif_gemm(const float* __restrict__ S,
                                                const float* __restrict__ W,
                                                float* __restrict__ I,
                                                int M, int N, int K) {
    __shared__ float As[TILE][TILE + 1];
    __shared__ float Bs[TILE][TILE + 1];
    const int m0 = blockIdx.x * TILE;
    const int n0 = blockIdx.y * TILE;
    const int tid = threadIdx.x;
    const int tx = tid & 15;
    const int ty = tid >> 4;
    float acc[4][4] = {{0.f, 0.f, 0.f, 0.f}};
    for (int k0 = 0; k0 < K; k0 += TILE) {
#pragma unroll
        for (int p = 0; p < 4; ++p) {
            const int idx = p * 256 + tid;
            const int r = idx >> 4;
            const int c = (idx & 15) << 2;
            const float4 a = *reinterpret_cast<const float4*>(
                S + (size_t)(m0 + r) * K + k0 + c);
            As[r][c + 0] = a.x; As[r][c + 1] = a.y;
            As[r][c + 2] = a.z; As[r][c + 3] = a.w;
            const float4 b = *reinterpret_cast<const float4*>(
                W + (size_t)(n0 + r) * K + k0 + c);
            Bs[r][c + 0] = b.x; Bs[r][c + 1] = b.y;
            Bs[r][c + 2] = b.z; Bs[r][c + 3] = b.w;
        }
        __syncthreads();
#pragma unroll
        for (int kk = 0; kk < TILE; ++kk) {
            float av[4], bv[4];
#pragma unroll
            for (int i = 0; i < 4; ++i) av[i] = As[ty * 4 + i][kk];
#pragma unroll
            for (int j = 0; j < 4; ++j) bv[j] = Bs[tx * 4 + j][kk];
#pragma unroll
            for (int i = 0; i < 4; ++i)
#pragma unroll
                for (int j = 0; j < 4; ++j)
                    acc[i][j] = fmaf(av[i], bv[j], acc[i][j]);
        }
        __syncthreads();
    }
#pragma unroll
    for (int i = 0; i < 4; ++i)
#pragma unroll
        for (int j = 0; j < 4; ++j)
            I[(size_t)(m0 + ty * 4 + i) * N + n0 + tx * 4 + j] = acc[i][j];
}

__global__ __launch_bounds__(256) void lif_scan(float* __restrict__ IO,
                                                int B, int T, int NO) {
    const int idx = blockIdx.x * blockDim.x + threadIdx.x;
    if (idx >= B * NO) return;
    const int b = idx / NO;
    const int o = idx % NO;
    float* p = IO + (size_t)b * T * NO + o;
    float v = 0.f;
    for (int t = 0; t < T; ++t) {
        const float cur = p[(size_t)t * NO];
        v = v * DECAY_F + cur;
        const float s = (v - 1.0f > 0.0f) ? 1.0f : 0.0f;
        v *= (1.0f - s);
        p[(size_t)t * NO] = s;
    }
}

extern "C" void kernel_launch(void* const* d_in, const int* in_sizes, int n_in,
                              void* d_out, int out_size, void* d_ws, size_t ws_size,
                              hipStream_t stream) {
    const float* S = (const float*)d_in[0];   // (B, T, n_in) binary spikes, fp32
    const float* W = (const float*)d_in[1];   // (n_out, n_in), fp32
    float* out = (float*)d_out;               // (B, T, n_out), fp32

    const int K = N_IN;
    const int M = in_sizes[0] / K;            // B*T = 32000
    const int B = 32;
    const int T = M / B;                      // 1000

    const size_t wt_bytes = (size_t)N_IN * N_OUT * sizeof(float);  // 2 MB

    if (ws_size >= wt_bytes && (M % 4) == 0) {
        float* WT = (float*)d_ws;
        dim3 tg(N_IN / 32, N_OUT / 32);       // 32 x 16
        transpose_w<<<tg, 256, 0, stream>>>(W, WT);
        gather_rows<<<M / 4, 256, 0, stream>>>(S, WT, out, M);
        lif_scan2<<<(B * N_OUT) / 256, 256, 0, stream>>>(out, T);
    } else {
        dim3 grid(M / TILE, N_OUT / TILE);
        lif_gemm<<<grid, 256, 0, stream>>>(S, W, out, M, N_OUT, K);
        lif_scan<<<(B * N_OUT + 255) / 256, 256, 0, stream>>>(out, B, T, N_OUT);
    }
}

// Round 5
// 147.494 us; speedup vs baseline: 6.3361x; 1.1196x over previous
//
#include <hip/hip_runtime.h>

// LIF spiking net forward, v4b — exact fixed-point i8 MFMA GEMM.
//   W -> 4 signed base-256 digits of round(W * 2^34)  (exact, top digit <=85)
//   S (binary fp32) -> i8
//   I = sum_d 2^(8d) * (S_i8 @ digit_d^T)  combined in int64, one fp32 round.
//   Quantization error <= 51 * 2^-35 ~ 1.5e-9  (100x below proven-safe noise).
// k1: s_to_i8   k2: w_digits   k3: gemm_i8 (32x32x32 i8 MFMA)   k4: lif_scan2
// v4b: LDS buffers addressed via offset macros (no pointer-array initializer,
// which hipcc rejects as a static addrspacecast initializer).

#define N_IN   1024
#define N_OUT  512
#define DECAY_F 0.95122942450071400910f
#define SCALE     17179869184.0            // 2^34
#define SCALE_INV 5.8207660913467407e-11f  // 2^-34

typedef int  v4i  __attribute__((ext_vector_type(4)));
typedef int  v16i __attribute__((ext_vector_type(16)));

// ---------------- kernel 1: S fp32 -> i8 ----------------
__global__ __launch_bounds__(256) void s_to_i8(const float* __restrict__ S,
                                               signed char* __restrict__ S8,
                                               int n16) {
    const int g = blockIdx.x * 256 + threadIdx.x;
    if (g >= n16) return;
    const float4* p = reinterpret_cast<const float4*>(S) + (size_t)g * 4;
    union { signed char c[16]; int4 v; } u;
#pragma unroll
    for (int q = 0; q < 4; ++q) {
        const float4 v = p[q];
        u.c[q * 4 + 0] = (signed char)(v.x != 0.f);
        u.c[q * 4 + 1] = (signed char)(v.y != 0.f);
        u.c[q * 4 + 2] = (signed char)(v.z != 0.f);
        u.c[q * 4 + 3] = (signed char)(v.w != 0.f);
    }
    reinterpret_cast<int4*>(S8)[g] = u.v;
}

// ---------------- kernel 2: W -> 4 digit planes ----------------
// D8 layout: row (d*512 + n), 1024 bytes per row (k-major).
__global__ __launch_bounds__(256) void w_digits(const float* __restrict__ W,
                                                signed char* __restrict__ D8) {
    const int n  = blockIdx.x;            // 0..511
    const int k0 = threadIdx.x * 4;       // 0..1020
    const float4 wv = *reinterpret_cast<const float4*>(W + (size_t)n * N_IN + k0);
    const float ww[4] = {wv.x, wv.y, wv.z, wv.w};
    int pk[4] = {0, 0, 0, 0};
#pragma unroll
    for (int j = 0; j < 4; ++j) {
        long long wi = (long long)rint((double)ww[j] * SCALE);
        const int d0 = (int)((wi + 128) & 255) - 128; wi = (wi - d0) >> 8;
        const int d1 = (int)((wi + 128) & 255) - 128; wi = (wi - d1) >> 8;
        const int d2 = (int)((wi + 128) & 255) - 128; wi = (wi - d2) >> 8;
        const int d3 = (int)wi;           // |d3| <= 85
        pk[0] |= (d0 & 255) << (8 * j);
        pk[1] |= (d1 & 255) << (8 * j);
        pk[2] |= (d2 & 255) << (8 * j);
        pk[3] |= (d3 & 255) << (8 * j);
    }
#pragma unroll
    for (int d = 0; d < 4; ++d)
        *reinterpret_cast<int*>(D8 + (size_t)(d * N_OUT + n) * N_IN + k0) = pk[d];
}

// ---------------- kernel 3: i8 MFMA GEMM ----------------
// BM=256, BN=64, BK=64; 512 threads = 8 waves (4 M x 2 N), wave tile 64x32.
// LDS pitch 80 (64+16 pad); A dbuf rows 0..255, B dbuf rows 0..255 (d*64+j).
#define BM 256
#define BN 64
#define BK 64
#define PITCH 80
#define ABUF (BM * PITCH)
#define ASH(buf) (lds + (buf) * ABUF)
#define BSH(buf) (lds + 2 * ABUF + (buf) * ABUF)

__global__ __launch_bounds__(512, 2) void gemm_i8(
        const signed char* __restrict__ S8,   // (M, 1024)
        const signed char* __restrict__ D8,   // (2048, 1024), row = d*512+n
        float* __restrict__ I, int M) {       // (M, 512)
    extern __shared__ signed char lds[];

    const int tid  = threadIdx.x;
    const int lane = tid & 63;
    const int w    = tid >> 6;          // 0..7
    const int wwm  = w >> 1;            // 0..3 -> M offset *64
    const int wwn  = w & 1;             // 0..1 -> N offset *32
    const int bn = blockIdx.x & 7;
    const int bm = blockIdx.x >> 3;
    const int m0 = bm * BM;
    const int n0 = bn * BN;

    // staging map: 16B per thread per issue; 512 thr * 16B = 8KB = 128 rows
    const int srow = tid >> 2;           // 0..127
    const int scol = (tid & 3) * 16;     // 0..48

    v16i acc[2][4];
#pragma unroll
    for (int mf = 0; mf < 2; ++mf)
#pragma unroll
        for (int d = 0; d < 4; ++d)
#pragma unroll
            for (int i = 0; i < 16; ++i) acc[mf][d][i] = 0;

    int4 ra0, ra1, rb0, rb1;
#define LOADT(kt)                                                                 \
    ra0 = *reinterpret_cast<const int4*>(S8 + (size_t)(m0 + srow) * N_IN + (kt) * BK + scol);        \
    ra1 = *reinterpret_cast<const int4*>(S8 + (size_t)(m0 + srow + 128) * N_IN + (kt) * BK + scol);  \
    rb0 = *reinterpret_cast<const int4*>(D8 + (size_t)(((srow >> 6) * N_OUT) + n0 + (srow & 63)) * N_IN + (kt) * BK + scol);            \
    rb1 = *reinterpret_cast<const int4*>(D8 + (size_t)(((srow >> 6) * N_OUT + 2 * N_OUT) + n0 + (srow & 63)) * N_IN + (kt) * BK + scol);

#define WRITET(buf)                                                               \
    *reinterpret_cast<int4*>(ASH(buf) + (srow) * PITCH + scol) = ra0;             \
    *reinterpret_cast<int4*>(ASH(buf) + (srow + 128) * PITCH + scol) = ra1;       \
    *reinterpret_cast<int4*>(BSH(buf) + (srow) * PITCH + scol) = rb0;             \
    *reinterpret_cast<int4*>(BSH(buf) + (srow + 128) * PITCH + scol) = rb1;

    LOADT(0);
    WRITET(0);
    __syncthreads();

    const int fr = lane & 31;                 // fragment row/col
    const int kh = (lane >> 5) * 16;          // k-half byte offset

    int cur = 0;
#pragma unroll 1
    for (int kt = 0; kt < N_IN / BK; ++kt) {
        if (kt < N_IN / BK - 1) { LOADT(kt + 1); }
#pragma unroll
        for (int ksub = 0; ksub < 2; ++ksub) {
            const int kb = ksub * 32 + kh;
            v4i af0 = *reinterpret_cast<const v4i*>(
                ASH(cur) + (wwm * 64 + fr) * PITCH + kb);
            v4i af1 = *reinterpret_cast<const v4i*>(
                ASH(cur) + (wwm * 64 + 32 + fr) * PITCH + kb);
            v4i bf[4];
#pragma unroll
            for (int d = 0; d < 4; ++d)
                bf[d] = *reinterpret_cast<const v4i*>(
                    BSH(cur) + (d * 64 + wwn * 32 + fr) * PITCH + kb);
#pragma unroll
            for (int d = 0; d < 4; ++d) {
                acc[0][d] = __builtin_amdgcn_mfma_i32_32x32x32_i8(af0, bf[d], acc[0][d], 0, 0, 0);
                acc[1][d] = __builtin_amdgcn_mfma_i32_32x32x32_i8(af1, bf[d], acc[1][d], 0, 0, 0);
            }
        }
        if (kt < N_IN / BK - 1) { WRITET(cur ^ 1); }
        __syncthreads();
        cur ^= 1;
    }

    // epilogue: combine digits in int64, one fp32 rounding
    const int col = fr;                       // n within 32
    const int rb_ = (lane >> 5) * 4;
#pragma unroll
    for (int mf = 0; mf < 2; ++mf) {
#pragma unroll
        for (int reg = 0; reg < 16; ++reg) {
            const int row = (reg & 3) + 8 * (reg >> 2) + rb_;
            const long long v =
                ((long long)acc[mf][3][reg] << 24) + ((long long)acc[mf][2][reg] << 16) +
                ((long long)acc[mf][1][reg] << 8) + (long long)acc[mf][0][reg];
            I[(size_t)(m0 + wwm * 64 + mf * 32 + row) * N_OUT + n0 + wwn * 32 + col] =
                (float)v * SCALE_INV;
        }
    }
}
#undef LOADT
#undef WRITET

// ---------------- kernel 4: LIF scan, in-place ----------------
#define UNROLL_T 40
__global__ __launch_bounds__(256) void lif_scan2(float* __restrict__ IO, int T) {
    const int idx = blockIdx.x * blockDim.x + threadIdx.x;
    const int b = idx >> 9, o = idx & (N_OUT - 1);
    float* p = IO + (size_t)b * T * N_OUT + o;
    float v = 0.f;
    for (int t0 = 0; t0 < T; t0 += UNROLL_T) {
        float c[UNROLL_T];
#pragma unroll
        for (int j = 0; j < UNROLL_T; ++j) c[j] = p[(size_t)(t0 + j) * N_OUT];
#pragma unroll
        for (int j = 0; j < UNROLL_T; ++j) {
            v = v * DECAY_F + c[j];
            float s = (v > 1.0f) ? 1.0f : 0.f;
            v *= (1.f - s);
            c[j] = s;
        }
#pragma unroll
        for (int j = 0; j < UNROLL_T; ++j) p[(size_t)(t0 + j) * N_OUT] = c[j];
    }
}

// ---------------- fallback: v3 gather path ----------------
__global__ __launch_bounds__(256) void transpose_w(const float* __restrict__ W,
                                                   float* __restrict__ WT) {
    __shared__ float t[32][33];
    const int k0 = blockIdx.x * 32;
    const int n0 = blockIdx.y * 32;
    const int lx = threadIdx.x & 31;
    const int ly = threadIdx.x >> 5;
#pragma unroll
    for (int r = ly; r < 32; r += 8)
        t[r][lx] = W[(size_t)(n0 + r) * N_IN + k0 + lx];
    __syncthreads();
#pragma unroll
    for (int r = ly; r < 32; r += 8)
        WT[(size_t)(k0 + r) * N_OUT + n0 + lx] = t[lx][r];
}

__global__ __launch_bounds__(256) void gather_rows(
        const float* __restrict__ S, const float* __restrict__ WT,
        float* __restrict__ I, int M) {
    const int wid  = blockIdx.x * 4 + (threadIdx.x >> 6);
    const int lane = threadIdx.x & 63;
    if (wid >= M) return;
    const float* srow = S + (size_t)wid * N_IN;
    float4 a0 = {0.f, 0.f, 0.f, 0.f};
    float4 a1 = {0.f, 0.f, 0.f, 0.f};
    float sv[16];
#pragma unroll
    for (int g = 0; g < 16; ++g) sv[g] = srow[g * 64 + lane];
#pragma unroll
    for (int g = 0; g < 16; ++g) {
        unsigned long long m = __ballot(sv[g] != 0.0f);
        while (m) {
            const int b = __builtin_ctzll(m);
            m &= m - 1;
            const int k = g * 64 + b;
            const float* wp = WT + (size_t)k * N_OUT + lane * 4;
            const float4 w0 = *reinterpret_cast<const float4*>(wp);
            const float4 w1 = *reinterpret_cast<const float4*>(wp + 256);
            a0.x += w0.x; a0.y += w0.y; a0.z += w0.z; a0.w += w0.w;
            a1.x += w1.x; a1.y += w1.y; a1.z += w1.z; a1.w += w1.w;
        }
    }
    float* op = I + (size_t)wid * N_OUT + lane * 4;
    *reinterpret_cast<float4*>(op) = a0;
    *reinterpret_cast<float4*>(op + 256) = a1;
}

extern "C" void kernel_launch(void* const* d_in, const int* in_sizes, int n_in,
                              void* d_out, int out_size, void* d_ws, size_t ws_size,
                              hipStream_t stream) {
    const float* S = (const float*)d_in[0];   // (B, T, n_in) binary spikes, fp32
    const float* W = (const float*)d_in[1];   // (n_out, n_in), fp32
    float* out = (float*)d_out;               // (B, T, n_out), fp32

    const int K = N_IN;
    const int M = in_sizes[0] / K;            // 32000
    const int B = 32;
    const int T = M / B;                      // 1000

    const size_t s8_bytes = (size_t)M * N_IN;                 // 32.77 MB
    const size_t d8_bytes = (size_t)4 * N_OUT * N_IN;         // 2 MB
    const size_t need = s8_bytes + d8_bytes;

    if (ws_size >= need && (M % BM) == 0) {
        signed char* S8 = (signed char*)d_ws;
        signed char* D8 = (signed char*)d_ws + s8_bytes;
        const int n16 = M * N_IN / 16;
        s_to_i8<<<(n16 + 255) / 256, 256, 0, stream>>>(S, S8, n16);
        w_digits<<<N_OUT, 256, 0, stream>>>(W, D8);
        const size_t lds_bytes = (size_t)4 * ABUF;            // 81920
        gemm_i8<<<(M / BM) * (N_OUT / BN), 512, lds_bytes, stream>>>(S8, D8, out, M);
        lif_scan2<<<(B * N_OUT) / 256, 256, 0, stream>>>(out, T);
    } else if (ws_size >= (size_t)N_IN * N_OUT * sizeof(float) && (M % 4) == 0) {
        float* WT = (float*)d_ws;
        dim3 tg(N_IN / 32, N_OUT / 32);
        transpose_w<<<tg, 256, 0, stream>>>(W, WT);
        gather_rows<<<M / 4, 256, 0, stream>>>(S, WT, out, M);
        lif_scan2<<<(B * N_OUT) / 256, 256, 0, stream>>>(out, T);
    }
}

// Round 6
// 142.135 us; speedup vs baseline: 6.5750x; 1.0377x over previous
//
#include <hip/hip_runtime.h>

// LIF spiking net forward, v5 — exact fixed-point i8 MFMA GEMM, pipelined.
//   W -> 4 signed base-256 digits of round(W * 2^34)  (exact, top digit <=85)
//   S (binary fp32) -> i8
//   I = sum_d 2^(8d) * (S_i8 @ digit_d^T)  combined in int64, one fp32 round.
//   Quantization error <= 51 * 2^-35 ~ 1.5e-9  (no spike flips; absmax 0.0).
// v5: depth-2 global->reg->LDS pipeline (counted vmcnt), setprio around MFMA,
//     XCD-aware block swizzle for A-tile L2 locality.

#define N_IN   1024
#define N_OUT  512
#define DECAY_F 0.95122942450071400910f
#define SCALE     17179869184.0            // 2^34
#define SCALE_INV 5.8207660913467407e-11f  // 2^-34

typedef int  v4i  __attribute__((ext_vector_type(4)));
typedef int  v16i __attribute__((ext_vector_type(16)));

// ---------------- kernel 1: S fp32 -> i8 ----------------
__global__ __launch_bounds__(256) void s_to_i8(const float* __restrict__ S,
                                               signed char* __restrict__ S8,
                                               int n16) {
    const int g = blockIdx.x * 256 + threadIdx.x;
    if (g >= n16) return;
    const float4* p = reinterpret_cast<const float4*>(S) + (size_t)g * 4;
    union { signed char c[16]; int4 v; } u;
#pragma unroll
    for (int q = 0; q < 4; ++q) {
        const float4 v = p[q];
        u.c[q * 4 + 0] = (signed char)(v.x != 0.f);
        u.c[q * 4 + 1] = (signed char)(v.y != 0.f);
        u.c[q * 4 + 2] = (signed char)(v.z != 0.f);
        u.c[q * 4 + 3] = (signed char)(v.w != 0.f);
    }
    reinterpret_cast<int4*>(S8)[g] = u.v;
}

// ---------------- kernel 2: W -> 4 digit planes ----------------
__global__ __launch_bounds__(256) void w_digits(const float* __restrict__ W,
                                                signed char* __restrict__ D8) {
    const int n  = blockIdx.x;            // 0..511
    const int k0 = threadIdx.x * 4;       // 0..1020
    const float4 wv = *reinterpret_cast<const float4*>(W + (size_t)n * N_IN + k0);
    const float ww[4] = {wv.x, wv.y, wv.z, wv.w};
    int pk[4] = {0, 0, 0, 0};
#pragma unroll
    for (int j = 0; j < 4; ++j) {
        long long wi = (long long)rint((double)ww[j] * SCALE);
        const int d0 = (int)((wi + 128) & 255) - 128; wi = (wi - d0) >> 8;
        const int d1 = (int)((wi + 128) & 255) - 128; wi = (wi - d1) >> 8;
        const int d2 = (int)((wi + 128) & 255) - 128; wi = (wi - d2) >> 8;
        const int d3 = (int)wi;           // |d3| <= 85
        pk[0] |= (d0 & 255) << (8 * j);
        pk[1] |= (d1 & 255) << (8 * j);
        pk[2] |= (d2 & 255) << (8 * j);
        pk[3] |= (d3 & 255) << (8 * j);
    }
#pragma unroll
    for (int d = 0; d < 4; ++d)
        *reinterpret_cast<int*>(D8 + (size_t)(d * N_OUT + n) * N_IN + k0) = pk[d];
}

// ---------------- kernel 3: i8 MFMA GEMM, depth-2 pipeline ----------------
#define BM 256
#define BN 64
#define BK 64
#define PITCH 80
#define ABUF (BM * PITCH)
#define ASH(buf) (lds + (buf) * ABUF)
#define BSH(buf) (lds + 2 * ABUF + (buf) * ABUF)

__global__ __launch_bounds__(512, 2) void gemm_i8(
        const signed char* __restrict__ S8,   // (M, 1024)
        const signed char* __restrict__ D8,   // (2048, 1024), row = d*512+n
        float* __restrict__ I, int M) {       // (M, 512)
    extern __shared__ signed char lds[];

    const int tid  = threadIdx.x;
    const int lane = tid & 63;
    const int w    = tid >> 6;
    const int wwm  = w >> 1;            // 0..3 -> M offset *64
    const int wwn  = w & 1;             // 0..1 -> N offset *32

    // XCD-aware swizzle: grid = 8*nx blocks (nx = M/BM). Map so each XCD's
    // round-robin share is a contiguous bm-range (A-tile reuse in its L2).
    const int nx  = M / BM;                       // 125
    const int u   = (blockIdx.x & 7) * nx + (blockIdx.x >> 3);
    const int bm  = u >> 3;
    const int bn  = u & 7;
    const int m0 = bm * BM;
    const int n0 = bn * BN;

    const int srow = tid >> 2;           // 0..127
    const int scol = (tid & 3) * 16;     // 0..48

    v16i acc[2][4];
#pragma unroll
    for (int mf = 0; mf < 2; ++mf)
#pragma unroll
        for (int d = 0; d < 4; ++d)
#pragma unroll
            for (int i = 0; i < 16; ++i) acc[mf][d][i] = 0;

    // two named register staging sets (compile-time indexed; rule #20)
    int4 pa0, pa1, pb0, pb1;
    int4 qa0, qa1, qb0, qb1;

#define LOADT(SET, kt)                                                            \
    SET##a0 = *reinterpret_cast<const int4*>(S8 + (size_t)(m0 + srow) * N_IN + (kt) * BK + scol);        \
    SET##a1 = *reinterpret_cast<const int4*>(S8 + (size_t)(m0 + srow + 128) * N_IN + (kt) * BK + scol);  \
    SET##b0 = *reinterpret_cast<const int4*>(D8 + (size_t)(((srow >> 6) * N_OUT) + n0 + (srow & 63)) * N_IN + (kt) * BK + scol);            \
    SET##b1 = *reinterpret_cast<const int4*>(D8 + (size_t)(((srow >> 6) * N_OUT + 2 * N_OUT) + n0 + (srow & 63)) * N_IN + (kt) * BK + scol);

#define WRITET(buf, SET)                                                          \
    *reinterpret_cast<int4*>(ASH(buf) + (srow) * PITCH + scol) = SET##a0;         \
    *reinterpret_cast<int4*>(ASH(buf) + (srow + 128) * PITCH + scol) = SET##a1;   \
    *reinterpret_cast<int4*>(BSH(buf) + (srow) * PITCH + scol) = SET##b0;         \
    *reinterpret_cast<int4*>(BSH(buf) + (srow + 128) * PITCH + scol) = SET##b1;

    const int fr = lane & 31;                 // fragment row/col
    const int kh = (lane >> 5) * 16;          // k-half byte offset

#define COMPUTE(buf)                                                              \
    _Pragma("unroll")                                                             \
    for (int ksub = 0; ksub < 2; ++ksub) {                                        \
        const int kb = ksub * 32 + kh;                                            \
        v4i af0 = *reinterpret_cast<const v4i*>(ASH(buf) + (wwm * 64 + fr) * PITCH + kb);       \
        v4i af1 = *reinterpret_cast<const v4i*>(ASH(buf) + (wwm * 64 + 32 + fr) * PITCH + kb);  \
        v4i bf[4];                                                                \
        _Pragma("unroll")                                                         \
        for (int d = 0; d < 4; ++d)                                               \
            bf[d] = *reinterpret_cast<const v4i*>(BSH(buf) + (d * 64 + wwn * 32 + fr) * PITCH + kb); \
        __builtin_amdgcn_s_setprio(1);                                            \
        _Pragma("unroll")                                                         \
        for (int d = 0; d < 4; ++d) {                                             \
            acc[0][d] = __builtin_amdgcn_mfma_i32_32x32x32_i8(af0, bf[d], acc[0][d], 0, 0, 0); \
            acc[1][d] = __builtin_amdgcn_mfma_i32_32x32x32_i8(af1, bf[d], acc[1][d], 0, 0, 0); \
        }                                                                         \
        __builtin_amdgcn_s_setprio(0);                                            \
    }

    // prologue: tile0 -> LDS buf0; tile1 -> p; tile2 -> q (in flight)
    LOADT(p, 0);
    WRITET(0, p);
    LOADT(p, 1);
    LOADT(q, 2);
    __syncthreads();

    // tiles: buf = t&1; odd tiles staged via p, even via q.
#pragma unroll 1
    for (int kt = 0; kt < 16; kt += 2) {
        // even iter: compute buf0 (tile kt); stage tile kt+1 from p into buf1
        WRITET(1, p);                          // kt+1 <= 15 always here
        if (kt + 3 <= 15) { LOADT(p, kt + 3); }
        COMPUTE(0);
        __syncthreads();
        // odd iter: compute buf1 (tile kt+1); stage tile kt+2 from q into buf0
        if (kt + 2 <= 15) {
            WRITET(0, q);
            if (kt + 4 <= 15) { LOADT(q, kt + 4); }
        }
        COMPUTE(1);
        __syncthreads();
    }

    // epilogue: combine digits in int64, one fp32 rounding
    const int col = fr;
    const int rb_ = (lane >> 5) * 4;
#pragma unroll
    for (int mf = 0; mf < 2; ++mf) {
#pragma unroll
        for (int reg = 0; reg < 16; ++reg) {
            const int row = (reg & 3) + 8 * (reg >> 2) + rb_;
            const long long v =
                ((long long)acc[mf][3][reg] << 24) + ((long long)acc[mf][2][reg] << 16) +
                ((long long)acc[mf][1][reg] << 8) + (long long)acc[mf][0][reg];
            I[(size_t)(m0 + wwm * 64 + mf * 32 + row) * N_OUT + n0 + wwn * 32 + col] =
                (float)v * SCALE_INV;
        }
    }
}
#undef LOADT
#undef WRITET
#undef COMPUTE

// ---------------- kernel 4: LIF scan, in-place ----------------
#define UNROLL_T 40
__global__ __launch_bounds__(256) void lif_scan2(float* __restrict__ IO, int T) {
    const int idx = blockIdx.x * blockDim.x + threadIdx.x;
    const int b = idx >> 9, o = idx & (N_OUT - 1);
    float* p = IO + (size_t)b * T * N_OUT + o;
    float v = 0.f;
    for (int t0 = 0; t0 < T; t0 += UNROLL_T) {
        float c[UNROLL_T];
#pragma unroll
        for (int j = 0; j < UNROLL_T; ++j) c[j] = p[(size_t)(t0 + j) * N_OUT];
#pragma unroll
        for (int j = 0; j < UNROLL_T; ++j) {
            v = v * DECAY_F + c[j];
            float s = (v > 1.0f) ? 1.0f : 0.f;
            v *= (1.f - s);
            c[j] = s;
        }
#pragma unroll
        for (int j = 0; j < UNROLL_T; ++j) p[(size_t)(t0 + j) * N_OUT] = c[j];
    }
}

// ---------------- fallback: v3 gather path ----------------
__global__ __launch_bounds__(256) void transpose_w(const float* __restrict__ W,
                                                   float* __restrict__ WT) {
    __shared__ float t[32][33];
    const int k0 = blockIdx.x * 32;
    const int n0 = blockIdx.y * 32;
    const int lx = threadIdx.x & 31;
    const int ly = threadIdx.x >> 5;
#pragma unroll
    for (int r = ly; r < 32; r += 8)
        t[r][lx] = W[(size_t)(n0 + r) * N_IN + k0 + lx];
    __syncthreads();
#pragma unroll
    for (int r = ly; r < 32; r += 8)
        WT[(size_t)(k0 + r) * N_OUT + n0 + lx] = t[lx][r];
}

__global__ __launch_bounds__(256) void gather_rows(
        const float* __restrict__ S, const float* __restrict__ WT,
        float* __restrict__ I, int M) {
    const int wid  = blockIdx.x * 4 + (threadIdx.x >> 6);
    const int lane = threadIdx.x & 63;
    if (wid >= M) return;
    const float* srow = S + (size_t)wid * N_IN;
    float4 a0 = {0.f, 0.f, 0.f, 0.f};
    float4 a1 = {0.f, 0.f, 0.f, 0.f};
    float sv[16];
#pragma unroll
    for (int g = 0; g < 16; ++g) sv[g] = srow[g * 64 + lane];
#pragma unroll
    for (int g = 0; g < 16; ++g) {
        unsigned long long m = __ballot(sv[g] != 0.0f);
        while (m) {
            const int b = __builtin_ctzll(m);
            m &= m - 1;
            const int k = g * 64 + b;
            const float* wp = WT + (size_t)k * N_OUT + lane * 4;
            const float4 w0 = *reinterpret_cast<const float4*>(wp);
            const float4 w1 = *reinterpret_cast<const float4*>(wp + 256);
            a0.x += w0.x; a0.y += w0.y; a0.z += w0.z; a0.w += w0.w;
            a1.x += w1.x; a1.y += w1.y; a1.z += w1.z; a1.w += w1.w;
        }
    }
    float* op = I + (size_t)wid * N_OUT + lane * 4;
    *reinterpret_cast<float4*>(op) = a0;
    *reinterpret_cast<float4*>(op + 256) = a1;
}

extern "C" void kernel_launch(void* const* d_in, const int* in_sizes, int n_in,
                              void* d_out, int out_size, void* d_ws, size_t ws_size,
                              hipStream_t stream) {
    const float* S = (const float*)d_in[0];   // (B, T, n_in) binary spikes, fp32
    const float* W = (const float*)d_in[1];   // (n_out, n_in), fp32
    float* out = (float*)d_out;               // (B, T, n_out), fp32

    const int K = N_IN;
    const int M = in_sizes[0] / K;            // 32000
    const int B = 32;
    const int T = M / B;                      // 1000

    const size_t s8_bytes = (size_t)M * N_IN;                 // 32.77 MB
    const size_t d8_bytes = (size_t)4 * N_OUT * N_IN;         // 2 MB
    const size_t need = s8_bytes + d8_bytes;

    if (ws_size >= need && (M % BM) == 0) {
        signed char* S8 = (signed char*)d_ws;
        signed char* D8 = (signed char*)d_ws + s8_bytes;
        const int n16 = M * N_IN / 16;
        s_to_i8<<<(n16 + 255) / 256, 256, 0, stream>>>(S, S8, n16);
        w_digits<<<N_OUT, 256, 0, stream>>>(W, D8);
        const size_t lds_bytes = (size_t)4 * ABUF;            // 81920
        gemm_i8<<<(M / BM) * (N_OUT / BN), 512, lds_bytes, stream>>>(S8, D8, out, M);
        lif_scan2<<<(B * N_OUT) / 256, 256, 0, stream>>>(out, T);
    } else if (ws_size >= (size_t)N_IN * N_OUT * sizeof(float) && (M % 4) == 0) {
        float* WT = (float*)d_ws;
        dim3 tg(N_IN / 32, N_OUT / 32);
        transpose_w<<<tg, 256, 0, stream>>>(W, WT);
        gather_rows<<<M / 4, 256, 0, stream>>>(S, WT, out, M);
        lif_scan2<<<(B * N_OUT) / 256, 256, 0, stream>>>(out, T);
    }
}